// Round 2
// baseline (4855.794 us; speedup 1.0000x reference)
//
#include <hip/hip_runtime.h>
#include <hip/hip_bf16.h>

// MatchLSTM boundary-pointer model on MI355X (gfx950).
// B=32 T=400 J=30 V=50000 D=150 H=150 L=2. Output [B,2,401].
//
// Round 2: round 1's per-thread weight arrays (float whr[150]) were NOT
// promoted by SROA (VGPR_Count=128, VALUBusy=7% -> scratch-latency bound).
// Fix: named float4 registers via macro expansion (no alloca possible),
// fed from zero-padded weight layouts (row stride 152 / transposed Wr with
// seg stride 52) so every load is an aligned float4 and the FMA loop is
// branchless. h lives in LDS with a zeroed tail; phase-A h reads are
// same-address b128 broadcasts (bank-conflict-free).

namespace {

constexpr int NBATCH = 32;
constexpr int TLEN   = 400;
constexpr int JQ     = 30;
constexpr int HID    = 150;
constexpr int T1     = 401;

__device__ __forceinline__ float sigm(float x){ return 1.f/(1.f+__expf(-x)); }
__device__ __forceinline__ float tanh_f(float x){
  float e = __expf(-2.f*fabsf(x));
  float t = (1.f-e)/(1.f+e);
  return x < 0.f ? -t : t;
}
__device__ __forceinline__ float bf2f(unsigned short u){
  union { unsigned int i; float f; } c; c.i = ((unsigned int)u)<<16; return c.f;
}

#define NW 29
struct WDesc { const void* src[NW]; int off[NW+1]; };

// ---- dtype sniff: bf16-packed words have concentrated bits[14:8].
__global__ void sniff_kernel(const unsigned int* __restrict__ bits, int* __restrict__ flag){
  __shared__ int cnt;
  if (threadIdx.x==0) cnt = 0;
  __syncthreads();
  int hit = 0;
  #pragma unroll
  for (int i=0;i<4;i++){
    unsigned int w = bits[threadIdx.x*4+i];
    unsigned int b = (w>>8)&0x7Fu;
    if (b==0u || (b>=0x38u && b<=0x3Fu)) hit++;
  }
  atomicAdd(&cnt, hit);
  __syncthreads();
  if (threadIdx.x==0) *flag = (cnt > 768) ? 1 : 0;
}

__global__ void convert_weights_kernel(WDesc d, float* __restrict__ out, const int* __restrict__ flag){
  const int isbf = *flag;
  const int total = d.off[NW];
  for (int e = blockIdx.x*blockDim.x+threadIdx.x; e < total; e += gridDim.x*blockDim.x){
    int j = 0;
    while (e >= d.off[j+1]) j++;
    int i = e - d.off[j];
    out[e] = isbf ? bf2f(((const unsigned short*)d.src[j])[i])
                  : ((const float*)d.src[j])[i];
  }
}

// dst[r*ldd+c] = c<cols ? src[r*cols+c] : 0
__global__ void padrows_kernel(const float* __restrict__ src, float* __restrict__ dst,
                               int rows, int cols, int ldd){
  int i = blockIdx.x*blockDim.x+threadIdx.x;
  if (i >= rows*ldd) return;
  int r = i/ldd, c = i-r*ldd;
  dst[i] = (c<cols) ? src[(size_t)r*cols+c] : 0.f;
}

// WrTp[k*156 + seg*52 + ii] = (ii<50) ? Wr[(seg*50+ii)*150 + k] : 0
__global__ void wrt_kernel(const float* __restrict__ Wr, float* __restrict__ WrTp){
  int i = blockIdx.x*blockDim.x+threadIdx.x;
  if (i >= 150*156) return;
  int k = i/156, rem = i-k*156, seg = rem/52, ii = rem-seg*52;
  WrTp[i] = (ii<50) ? Wr[(size_t)(seg*50+ii)*150 + k] : 0.f;
}

// ---- generic row-tiled projection (unchanged from round 1)
__global__ __launch_bounds__(512) void rowproj_kernel(
    const float* __restrict__ Xrows,
    const int* __restrict__ gather, const void* __restrict__ Etab, const int* __restrict__ bfflag,
    const float* __restrict__ W, const float* __restrict__ bias,
    float* __restrict__ out, int rows, int K, int inner, int mode, int ldw, int offw)
{
  __shared__ float xs[8][304];
  const int r0 = blockIdx.x*8;
  int nr = rows - r0; if (nr > 8) nr = 8;
  if (nr <= 0) return;
  const int isbf = gather ? *bfflag : 0;
  for (int e = threadIdx.x; e < nr*inner; e += blockDim.x){
    int r = e/inner, i = e - r*inner;
    float v;
    if (gather){
      size_t base = (size_t)gather[r0+r]*inner + i;
      v = isbf ? bf2f(((const unsigned short*)Etab)[base]) : ((const float*)Etab)[base];
    } else {
      v = Xrows[(size_t)(r0+r)*inner + i];
    }
    xs[r][i] = v;
  }
  __syncthreads();
  for (int k = threadIdx.x; k < K; k += blockDim.x){
    float b0 = bias ? bias[k] : 0.f;
    float acc[8];
    #pragma unroll
    for (int r=0;r<8;r++) acc[r] = b0;
    if (mode==0){
      for (int i=0;i<inner;i++){
        float wv = W[(size_t)i*ldw + k];
        #pragma unroll
        for (int r=0;r<8;r++) acc[r] += xs[r][i]*wv;
      }
    } else {
      const float* wr = W + (size_t)k*ldw + offw;
      for (int i=0;i<inner;i++){
        float wv = wr[i];
        #pragma unroll
        for (int r=0;r<8;r++) acc[r] += xs[r][i]*wv;
      }
    }
    for (int r=0;r<nr;r++) out[(size_t)(r0+r)*K + k] = acc[r];
  }
}

// ---- register-forcing macros --------------------------------------------
#define R13(M) M(0) M(1) M(2) M(3) M(4) M(5) M(6) M(7) M(8) M(9) M(10) M(11) M(12)
#define R38(M) R13(M) M(13) M(14) M(15) M(16) M(17) M(18) M(19) M(20) M(21) M(22) \
               M(23) M(24) M(25) M(26) M(27) M(28) M(29) M(30) M(31) M(32) M(33) \
               M(34) M(35) M(36) M(37)

#define DECA(i) float4 wa##i;
#define LDA(i)  wa##i = wp4[i];
#define FMA_A(i) { float4 hv = h4[i]; \
  a0 = fmaf(hv.x, wa##i.x, a0); a1 = fmaf(hv.y, wa##i.y, a1); \
  a2 = fmaf(hv.z, wa##i.z, a2); a3 = fmaf(hv.w, wa##i.w, a3); }

#define DECR(i) float4 wr##i;
#define LDR(i)  wr##i = wq4[i];
#define FMA_R(i) { float2 hu = h2[hb2 + 2*(i)]; float2 hw2 = h2[hb2 + 2*(i) + 1]; \
  b0 = fmaf(hu.x,  wr##i.x, b0); b1 = fmaf(hu.y,  wr##i.y, b1); \
  b2 = fmaf(hw2.x, wr##i.z, b2); b3 = fmaf(hw2.y, wr##i.w, b3); }

// ---- merged GRU encoder scan: blocks 0..31 = context, 32..63 = query.
// Whh rows (padded to 152, zero tail) in named float4 registers.
__global__ __launch_bounds__(512) void gru_scan_kernel(
    const float* __restrict__ gi0, const float* __restrict__ W0P,
    const float* __restrict__ bh0, float* __restrict__ H0, int S0,
    const float* __restrict__ gi1, const float* __restrict__ W1P,
    const float* __restrict__ bh1, float* __restrict__ H1, int S1)
{
  const int blk = blockIdx.x;
  const float* gi; const float* WP; const float* bh; float* Hs; int S;
  if (blk < 32){ gi = gi0 + (size_t)blk*S0*450;      WP = W0P; bh = bh0;
                 Hs = H0 + (size_t)blk*S0*HID;       S = S0; }
  else         { int bb = blk-32;
                 gi = gi1 + (size_t)bb*S1*450;       WP = W1P; bh = bh1;
                 Hs = H1 + (size_t)bb*S1*HID;        S = S1; }
  __shared__ float h[152];
  __shared__ float gh[456];
  const int tid = threadIdx.x;
  R38(DECA)
  float br = 0.f;
  if (tid < 450){
    const float4* wp4 = (const float4*)(WP + (size_t)tid*152);
    R38(LDA)
    br = bh[tid];
  }
  if (tid < 152) h[tid] = 0.f;
  __syncthreads();
  const float4* h4 = (const float4*)h;
  for (int t=0;t<S;t++){
    float g0=0.f,g1=0.f,g2=0.f;
    if (tid < 150){
      const float* g = gi + (size_t)t*450;
      g0 = g[tid]; g1 = g[150+tid]; g2 = g[300+tid];
    }
    if (tid < 450){
      float a0=0.f,a1=0.f,a2=0.f,a3=0.f;
      R38(FMA_A)
      gh[tid] = br + (a0+a1) + (a2+a3);
    }
    __syncthreads();
    if (tid < 150){
      float r = sigm(g0 + gh[tid]);
      float z = sigm(g1 + gh[150+tid]);
      float n = tanh_f(g2 + r*gh[300+tid]);
      float hn = (1.f-z)*n + z*h[tid];
      h[tid] = hn;
      Hs[(size_t)t*HID + tid] = hn;
    }
    __syncthreads();
  }
}

__global__ void zero_hr0_kernel(float* __restrict__ Hr){
  int idx = blockIdx.x*blockDim.x + threadIdx.x;
  if (idx < NBATCH*300){
    int b = idx/300, k = idx - 300*b;
    Hr[(size_t)b*T1*300 + k] = 0.f;
  }
}

// ---- match scan: one block per (batch, dir). Whh row (38 float4) + Wr
// transposed column segment (13 float4) pinned in named registers.
__global__ __launch_bounds__(512) void match_scan_kernel(
    const float* __restrict__ pWp,   // [B,T,150]  Hp@Wp + gate_bias
    const float* __restrict__ whq,   // [B,J,150]  Hq@Wq
    const float* __restrict__ giXf,  // [B,T,450]  Hp@m_Wih_x^T + m_bih
    const float* __restrict__ giXr,
    const float* __restrict__ Pf,    // [B,J,450]  Hq@m_Wih_q^T
    const float* __restrict__ Pr,
    const float* __restrict__ mWhhP, const float* __restrict__ mrWhhP, // [450,152] padded
    const float* __restrict__ m_bhh, const float* __restrict__ mr_bhh,
    const float* __restrict__ WrTp,  // [150,156] transposed, seg-padded
    const float* __restrict__ wvec,  // [150]
    float* __restrict__ Hr)          // [B,401,300]
{
  const int b   = blockIdx.x;
  const int dir = blockIdx.y;
  const float* giX = dir ? giXr : giXf;
  const float* P   = dir ? Pr   : Pf;
  const float* WP  = dir ? mrWhhP : mWhhP;
  const float* bhh = dir ? mr_bhh : m_bhh;

  __shared__ float Pl[13500];      // 54 KB
  __shared__ float wl[152];
  __shared__ float h[152];
  __shared__ float pA[456];
  __shared__ float sc[32], attw[32];
  __shared__ float gis[456], ghs[456];

  const int tid = threadIdx.x;
  const int lane = tid & 63;
  const int wv = tid >> 6;

  R38(DECA)
  R13(DECR)
  float br = 0.f;
  const int kw  = (tid < 450) ? (tid % 150) : 0;
  const int seg = (tid < 450) ? (tid / 150) : 0;
  const int hb2 = seg*25;          // float2 index of h[seg*50]
  if (tid < 450){
    const float4* wp4 = (const float4*)(WP + (size_t)tid*152);
    R38(LDA)
    br = bhh[tid];
    const float4* wq4 = (const float4*)(WrTp + (size_t)kw*156 + seg*52);
    R13(LDR)
  }
  for (int e=tid; e<13500; e+=blockDim.x) Pl[e] = P[(size_t)b*13500 + e];
  if (tid < 152){ wl[tid] = (tid<150)?wvec[tid]:0.f; h[tid] = 0.f; }
  __syncthreads();
  const float4* h4 = (const float4*)h;
  const float2* h2 = (const float2*)h;

  const float* wq = whq + (size_t)b*JQ*150;
  for (int t=0;t<TLEN;t++){
    const int tt = dir ? (TLEN-1-t) : t;
    const float* pw = pWp + ((size_t)b*TLEN + tt)*150;
    float gv = (tid < 450) ? giX[((size_t)b*TLEN + tt)*450 + tid] : 0.f;
    float pw0 = pw[lane];
    float pw1 = pw[lane+64];
    float pw2 = (lane+128 < 150) ? pw[lane+128] : 0.f;

    // A: gh = bhh + h@Whh^T (regs) and Wr partials (regs)
    if (tid < 450){
      float a0=0.f,a1=0.f,a2=0.f,a3=0.f;
      R38(FMA_A)
      ghs[tid] = br + (a0+a1) + (a2+a3);
      float b0=0.f,b1=0.f,b2=0.f,b3=0.f;
      R13(FMA_R)
      pA[tid] = (b0+b1) + (b2+b3);
    }
    __syncthreads();

    // B: s[j] = sum_h w[h]*tanh(whq[j,h] + pWp[h] + hWr[h])
    for (int j=wv; j<JQ; j+=8){
      float acc = 0.f;
      {
        float hw = pA[lane] + pA[150+lane] + pA[300+lane];
        acc += wl[lane]*tanh_f(wq[j*150+lane] + pw0 + hw);
      }
      {
        int hh = lane+64;
        float hw = pA[hh] + pA[150+hh] + pA[300+hh];
        acc += wl[hh]*tanh_f(wq[j*150+hh] + pw1 + hw);
      }
      if (lane+128 < 150){
        int hh = lane+128;
        float hw = pA[hh] + pA[150+hh] + pA[300+hh];
        acc += wl[hh]*tanh_f(wq[j*150+hh] + pw2 + hw);
      }
      #pragma unroll
      for (int off=32; off; off>>=1) acc += __shfl_down(acc, off);
      if (lane==0) sc[j] = acc;
    }
    __syncthreads();

    // C: softmax over J=30
    if (tid < 64){
      float v = (tid < JQ) ? sc[tid] : -1e30f;
      float m = v;
      #pragma unroll
      for (int off=32; off; off>>=1) m = fmaxf(m, __shfl_down(m, off));
      m = __shfl(m, 0);
      float e = (tid < JQ) ? __expf(v-m) : 0.f;
      float s = e;
      #pragma unroll
      for (int off=32; off; off>>=1) s += __shfl_down(s, off);
      s = __shfl(s, 0);
      if (tid < JQ) attw[tid] = e/s;
    }
    __syncthreads();

    // D: gi = giX + sum_j attw[j]*P[j,:]
    if (tid < 450){
      float a0 = gv, a1 = 0.f;
      #pragma unroll
      for (int j=0;j<JQ;j+=2){
        a0 += attw[j]  *Pl[j*450+tid];
        a1 += attw[j+1]*Pl[(j+1)*450+tid];
      }
      gis[tid] = a0+a1;
    }
    __syncthreads();

    // E: GRU combine, write Hr[b, t+1, dir*150 + k]
    if (tid < 150){
      float r = sigm(gis[tid] + ghs[tid]);
      float z = sigm(gis[150+tid] + ghs[150+tid]);
      float n = tanh_f(gis[300+tid] + r*ghs[300+tid]);
      float hn = (1.f-z)*n + z*h[tid];
      h[tid] = hn;
      Hr[((size_t)b*T1 + (t+1))*300 + dir*150 + tid] = hn;
    }
    __syncthreads();
  }
}

// ---- pointer decoder (unchanged)
__global__ __launch_bounds__(512,2) void ptr_scan_kernel(
    const float* __restrict__ enc, const float* __restrict__ Hr,
    const float* __restrict__ W2, const float* __restrict__ pv,
    const float* __restrict__ dWih, const float* __restrict__ dWhh,
    const float* __restrict__ dbih, const float* __restrict__ dbhh,
    void* __restrict__ outv, const int* __restrict__ flag)
{
  const int b = blockIdx.x;
  const int tid = threadIdx.x;
  const int isbf = *flag;
  __shared__ float h[300], hW2[300], sl[T1], al[T1], c[300];
  __shared__ float gis[900], ghs[900];
  __shared__ float vl[300];
  __shared__ float red[8];
  if (tid < 300){ h[tid] = 0.f; vl[tid] = pv[tid]; }
  __syncthreads();
  for (int l=0;l<2;l++){
    if (tid < 300){
      float a0=0.f,a1=0.f;
      for (int i=0;i<300;i+=2){
        a0 += h[i]  *W2[(size_t)i*300+tid];
        a1 += h[i+1]*W2[(size_t)(i+1)*300+tid];
      }
      hW2[tid] = a0+a1;
    }
    __syncthreads();
    {
      const int wv = tid>>6, lane = tid&63;
      for (int t=wv; t<T1; t+=8){
        const float* er = enc + ((size_t)b*T1 + t)*300;
        float acc = 0.f;
        for (int k=lane; k<300; k+=64) acc += vl[k]*tanh_f(er[k] + hW2[k]);
        #pragma unroll
        for (int off=32; off; off>>=1) acc += __shfl_down(acc, off);
        if (lane==0) sl[t] = acc;
      }
    }
    __syncthreads();
    {
      float v = (tid < T1) ? sl[tid] : -1e30f;
      float m = v;
      #pragma unroll
      for (int off=32; off; off>>=1) m = fmaxf(m, __shfl_down(m, off));
      if ((tid&63)==0) red[tid>>6] = m;
      __syncthreads();
      float bm = fmaxf(fmaxf(fmaxf(red[0],red[1]),fmaxf(red[2],red[3])),
                       fmaxf(fmaxf(red[4],red[5]),fmaxf(red[6],red[7])));
      float e = (tid < T1) ? __expf(v-bm) : 0.f;
      float s = e;
      #pragma unroll
      for (int off=32; off; off>>=1) s += __shfl_down(s, off);
      __syncthreads();
      if ((tid&63)==0) red[tid>>6] = s;
      __syncthreads();
      float bs = red[0]+red[1]+red[2]+red[3]+red[4]+red[5]+red[6]+red[7];
      if (tid < T1){
        float a = e/bs;
        al[tid] = a;
        size_t oi = ((size_t)b*2 + l)*T1 + tid;
        if (isbf) ((__hip_bfloat16*)outv)[oi] = __float2bfloat16(a);
        else      ((float*)outv)[oi] = a;
      }
    }
    __syncthreads();
    if (tid < 300){
      float acc = 0.f;
      for (int t=0;t<T1;t++) acc += al[t]*Hr[((size_t)b*T1 + t)*300 + tid];
      c[tid] = acc;
    }
    __syncthreads();
    for (int k=tid; k<900; k+=blockDim.x){
      const float* wi = dWih + (size_t)k*300;
      const float* wh = dWhh + (size_t)k*300;
      float a0 = dbih[k], a1 = dbhh[k];
      for (int i=0;i<300;i++){ a0 += c[i]*wi[i]; a1 += h[i]*wh[i]; }
      gis[k] = a0; ghs[k] = a1;
    }
    __syncthreads();
    if (tid < 300){
      float r = sigm(gis[tid] + ghs[tid]);
      float z = sigm(gis[300+tid] + ghs[300+tid]);
      float n = tanh_f(gis[600+tid] + r*ghs[600+tid]);
      h[tid] = (1.f-z)*n + z*h[tid];
    }
    __syncthreads();
  }
}

} // namespace

extern "C" void kernel_launch(void* const* d_in, const int* in_sizes, int n_in,
                              void* d_out, int out_size, void* d_ws, size_t ws_size,
                              hipStream_t stream)
{
  (void)in_sizes; (void)n_in; (void)out_size; (void)ws_size;
  float* ws = (float*)d_ws;
  int* flag = (int*)d_ws;

  static const int wsz[NW] = {
    67500,67500,450,450,
    67500,67500,450,450,
    22500,22500,22500,150,150,1,
    135000,67500,450,450,
    135000,67500,450,450,
    90000,90000,300,
    270000,270000,900,900
  };
  WDesc desc;
  int cum = 0;
  for (int j=0;j<NW;j++){ desc.src[j] = d_in[3+j]; desc.off[j] = cum; cum += wsz[j]; }
  desc.off[NW] = cum;

  float* WB = ws + 16;
  const float* P_ctx_Wih = WB + desc.off[0];
  const float* P_ctx_Whh = WB + desc.off[1];
  const float* P_ctx_bih = WB + desc.off[2];
  const float* P_ctx_bhh = WB + desc.off[3];
  const float* P_q_Wih   = WB + desc.off[4];
  const float* P_q_Whh   = WB + desc.off[5];
  const float* P_q_bih   = WB + desc.off[6];
  const float* P_q_bhh   = WB + desc.off[7];
  const float* P_Wq      = WB + desc.off[8];
  const float* P_Wp      = WB + desc.off[9];
  const float* P_Wr      = WB + desc.off[10];
  const float* P_w       = WB + desc.off[11];
  const float* P_gb      = WB + desc.off[12];
  const float* P_m_Wih   = WB + desc.off[14];
  const float* P_m_Whh   = WB + desc.off[15];
  const float* P_m_bih   = WB + desc.off[16];
  const float* P_m_bhh   = WB + desc.off[17];
  const float* P_mr_Wih  = WB + desc.off[18];
  const float* P_mr_Whh  = WB + desc.off[19];
  const float* P_mr_bih  = WB + desc.off[20];
  const float* P_mr_bhh  = WB + desc.off[21];
  const float* P_W1      = WB + desc.off[22];
  const float* P_W2      = WB + desc.off[23];
  const float* P_pv      = WB + desc.off[24];
  const float* P_dWih    = WB + desc.off[25];
  const float* P_dWhh    = WB + desc.off[26];
  const float* P_dbih    = WB + desc.off[27];
  const float* P_dbhh    = WB + desc.off[28];

  // padded weight layouts
  size_t p = 16 + 1468512;
  float* ctxWhhP = ws + p; p += 68400;   // [450,152]
  float* qWhhP   = ws + p; p += 68400;
  float* mWhhP   = ws + p; p += 68400;
  float* mrWhhP  = ws + p; p += 68400;
  float* WrTp    = ws + p; p += 23400;   // [150,156]

  float* ctx_gi = ws + p; p += 5760000;
  float* q_gi   = ws + p; p += 432000;
  float* HpB    = ws + p; p += 1920000;
  float* HqB    = ws + p; p += 144000;
  float* whqB   = ws + p; p += 144000;
  float* PfB    = ws + p; p += 432000;
  float* PrB    = ws + p; p += 432000;
  float* pWpB   = ws + p; p += 1920000;
  float* giXfB  = ws + p; p += 5760000;
  float* giXrB  = ws + p; p += 5760000;
  float* HrB    = ws + p; p += 3849600;
  float* encB   = ctx_gi;                // reuse (dead by then)

  // 1) dtype sniff + weight conversion + padded layouts
  sniff_kernel<<<1,256,0,stream>>>((const unsigned int*)d_in[2], flag);
  convert_weights_kernel<<<512,256,0,stream>>>(desc, WB, flag);
  padrows_kernel<<<(450*152+255)/256,256,0,stream>>>(P_ctx_Whh, ctxWhhP, 450,150,152);
  padrows_kernel<<<(450*152+255)/256,256,0,stream>>>(P_q_Whh,   qWhhP,   450,150,152);
  padrows_kernel<<<(450*152+255)/256,256,0,stream>>>(P_m_Whh,   mWhhP,   450,150,152);
  padrows_kernel<<<(450*152+255)/256,256,0,stream>>>(P_mr_Whh,  mrWhhP,  450,150,152);
  wrt_kernel<<<(150*156+255)/256,256,0,stream>>>(P_Wr, WrTp);

  // 2) embedding + input projections for both encoders
  rowproj_kernel<<<1600,512,0,stream>>>(nullptr,(const int*)d_in[0], d_in[2], flag,
                                        P_ctx_Wih, P_ctx_bih, ctx_gi, 12800,450,150,1,150,0);
  rowproj_kernel<<<120,512,0,stream>>>(nullptr,(const int*)d_in[1], d_in[2], flag,
                                       P_q_Wih, P_q_bih, q_gi, 960,450,150,1,150,0);

  // 3) encoder scans (merged: 32 ctx blocks + 32 query blocks)
  gru_scan_kernel<<<64,512,0,stream>>>(ctx_gi, ctxWhhP, P_ctx_bhh, HpB, 400,
                                       q_gi,   qWhhP,   P_q_bhh,   HqB, 30);

  // 4) Hq/Hp-dependent precomputations
  rowproj_kernel<<<120,192,0,stream>>>(HqB,nullptr,nullptr,nullptr, P_Wq, nullptr,
                                       whqB, 960,150,150,0,150,0);
  rowproj_kernel<<<120,512,0,stream>>>(HqB,nullptr,nullptr,nullptr, P_m_Wih, nullptr,
                                       PfB, 960,450,150,1,300,150);
  rowproj_kernel<<<120,512,0,stream>>>(HqB,nullptr,nullptr,nullptr, P_mr_Wih, nullptr,
                                       PrB, 960,450,150,1,300,150);
  rowproj_kernel<<<1600,192,0,stream>>>(HpB,nullptr,nullptr,nullptr, P_Wp, P_gb,
                                        pWpB, 12800,150,150,0,150,0);
  rowproj_kernel<<<1600,512,0,stream>>>(HpB,nullptr,nullptr,nullptr, P_m_Wih, P_m_bih,
                                        giXfB, 12800,450,150,1,300,0);
  rowproj_kernel<<<1600,512,0,stream>>>(HpB,nullptr,nullptr,nullptr, P_mr_Wih, P_mr_bih,
                                        giXrB, 12800,450,150,1,300,0);

  // 5) match scans (fwd+bwd concurrent)
  zero_hr0_kernel<<<(NBATCH*300+511)/512,512,0,stream>>>(HrB);
  match_scan_kernel<<<dim3(NBATCH,2),512,0,stream>>>(pWpB, whqB, giXfB, giXrB,
                                                     PfB, PrB, mWhhP, mrWhhP,
                                                     P_m_bhh, P_mr_bhh, WrTp, P_w, HrB);

  // 6) pointer decoder
  rowproj_kernel<<<1604,320,0,stream>>>(HrB,nullptr,nullptr,nullptr, P_W1, nullptr,
                                        encB, 12832,300,300,0,300,0);
  ptr_scan_kernel<<<32,512,0,stream>>>(encB, HrB, P_W2, P_pv,
                                       P_dWih, P_dWhh, P_dbih, P_dbhh, d_out, flag);
}

// Round 3
// 4690.368 us; speedup vs baseline: 1.0353x; 1.0353x over previous
//
#include <hip/hip_runtime.h>
#include <hip/hip_bf16.h>

// MatchLSTM boundary-pointer model on MI355X (gfx950).
// B=32 T=400 J=30 V=50000 D=150 H=150 L=2. Output [B,2,401].
//
// Round 3: round 2 still spilled (VGPR_Count=128, WRITE_SIZE up 5MB from
// scratch stores). Root cause: LDS=60KB permits 4 waves/EU, so the backend
// TARGETS 4 waves/EU and caps VGPRs at 128; __launch_bounds__'s 2nd arg only
// raises the occupancy floor, never lowers the target. Fix:
// amdgpu_waves_per_eu(2,2) pins the target at 2 waves/EU -> 256-VGPR budget,
// letting the 51 (match) / 38 (gru) named float4 weight registers actually
// live in VGPRs. Grid is 64 blocks on 256 CUs, so 1 block/CU costs nothing.

namespace {

constexpr int NBATCH = 32;
constexpr int TLEN   = 400;
constexpr int JQ     = 30;
constexpr int HID    = 150;
constexpr int T1     = 401;

__device__ __forceinline__ float sigm(float x){ return 1.f/(1.f+__expf(-x)); }
__device__ __forceinline__ float tanh_f(float x){
  float e = __expf(-2.f*fabsf(x));
  float t = (1.f-e)/(1.f+e);
  return x < 0.f ? -t : t;
}
__device__ __forceinline__ float bf2f(unsigned short u){
  union { unsigned int i; float f; } c; c.i = ((unsigned int)u)<<16; return c.f;
}

#define NW 29
struct WDesc { const void* src[NW]; int off[NW+1]; };

// ---- dtype sniff: bf16-packed words have concentrated bits[14:8].
__global__ void sniff_kernel(const unsigned int* __restrict__ bits, int* __restrict__ flag){
  __shared__ int cnt;
  if (threadIdx.x==0) cnt = 0;
  __syncthreads();
  int hit = 0;
  #pragma unroll
  for (int i=0;i<4;i++){
    unsigned int w = bits[threadIdx.x*4+i];
    unsigned int b = (w>>8)&0x7Fu;
    if (b==0u || (b>=0x38u && b<=0x3Fu)) hit++;
  }
  atomicAdd(&cnt, hit);
  __syncthreads();
  if (threadIdx.x==0) *flag = (cnt > 768) ? 1 : 0;
}

__global__ void convert_weights_kernel(WDesc d, float* __restrict__ out, const int* __restrict__ flag){
  const int isbf = *flag;
  const int total = d.off[NW];
  for (int e = blockIdx.x*blockDim.x+threadIdx.x; e < total; e += gridDim.x*blockDim.x){
    int j = 0;
    while (e >= d.off[j+1]) j++;
    int i = e - d.off[j];
    out[e] = isbf ? bf2f(((const unsigned short*)d.src[j])[i])
                  : ((const float*)d.src[j])[i];
  }
}

// dst[r*ldd+c] = c<cols ? src[r*cols+c] : 0
__global__ void padrows_kernel(const float* __restrict__ src, float* __restrict__ dst,
                               int rows, int cols, int ldd){
  int i = blockIdx.x*blockDim.x+threadIdx.x;
  if (i >= rows*ldd) return;
  int r = i/ldd, c = i-r*ldd;
  dst[i] = (c<cols) ? src[(size_t)r*cols+c] : 0.f;
}

// WrTp[k*156 + seg*52 + ii] = (ii<50) ? Wr[(seg*50+ii)*150 + k] : 0
__global__ void wrt_kernel(const float* __restrict__ Wr, float* __restrict__ WrTp){
  int i = blockIdx.x*blockDim.x+threadIdx.x;
  if (i >= 150*156) return;
  int k = i/156, rem = i-k*156, seg = rem/52, ii = rem-seg*52;
  WrTp[i] = (ii<50) ? Wr[(size_t)(seg*50+ii)*150 + k] : 0.f;
}

// ---- generic row-tiled projection
__global__ __launch_bounds__(512) void rowproj_kernel(
    const float* __restrict__ Xrows,
    const int* __restrict__ gather, const void* __restrict__ Etab, const int* __restrict__ bfflag,
    const float* __restrict__ W, const float* __restrict__ bias,
    float* __restrict__ out, int rows, int K, int inner, int mode, int ldw, int offw)
{
  __shared__ float xs[8][304];
  const int r0 = blockIdx.x*8;
  int nr = rows - r0; if (nr > 8) nr = 8;
  if (nr <= 0) return;
  const int isbf = gather ? *bfflag : 0;
  for (int e = threadIdx.x; e < nr*inner; e += blockDim.x){
    int r = e/inner, i = e - r*inner;
    float v;
    if (gather){
      size_t base = (size_t)gather[r0+r]*inner + i;
      v = isbf ? bf2f(((const unsigned short*)Etab)[base]) : ((const float*)Etab)[base];
    } else {
      v = Xrows[(size_t)(r0+r)*inner + i];
    }
    xs[r][i] = v;
  }
  __syncthreads();
  for (int k = threadIdx.x; k < K; k += blockDim.x){
    float b0 = bias ? bias[k] : 0.f;
    float acc[8];
    #pragma unroll
    for (int r=0;r<8;r++) acc[r] = b0;
    if (mode==0){
      for (int i=0;i<inner;i++){
        float wv = W[(size_t)i*ldw + k];
        #pragma unroll
        for (int r=0;r<8;r++) acc[r] += xs[r][i]*wv;
      }
    } else {
      const float* wr = W + (size_t)k*ldw + offw;
      for (int i=0;i<inner;i++){
        float wv = wr[i];
        #pragma unroll
        for (int r=0;r<8;r++) acc[r] += xs[r][i]*wv;
      }
    }
    for (int r=0;r<nr;r++) out[(size_t)(r0+r)*K + k] = acc[r];
  }
}

// ---- register-forcing macros --------------------------------------------
#define R13(M) M(0) M(1) M(2) M(3) M(4) M(5) M(6) M(7) M(8) M(9) M(10) M(11) M(12)
#define R38(M) R13(M) M(13) M(14) M(15) M(16) M(17) M(18) M(19) M(20) M(21) M(22) \
               M(23) M(24) M(25) M(26) M(27) M(28) M(29) M(30) M(31) M(32) M(33) \
               M(34) M(35) M(36) M(37)

#define DECA(i) float4 wa##i;
#define LDA(i)  wa##i = wp4[i];
#define FMA_A(i) { float4 hv = h4[i]; \
  a0 = fmaf(hv.x, wa##i.x, a0); a1 = fmaf(hv.y, wa##i.y, a1); \
  a2 = fmaf(hv.z, wa##i.z, a2); a3 = fmaf(hv.w, wa##i.w, a3); }

#define DECR(i) float4 wr##i;
#define LDR(i)  wr##i = wq4[i];
#define FMA_R(i) { float2 hu = h2[hb2 + 2*(i)]; float2 hw2 = h2[hb2 + 2*(i) + 1]; \
  b0 = fmaf(hu.x,  wr##i.x, b0); b1 = fmaf(hu.y,  wr##i.y, b1); \
  b2 = fmaf(hw2.x, wr##i.z, b2); b3 = fmaf(hw2.y, wr##i.w, b3); }

// ---- merged GRU encoder scan: blocks 0..31 = context, 32..63 = query.
__global__ __launch_bounds__(512)
__attribute__((amdgpu_waves_per_eu(2, 2)))
void gru_scan_kernel(
    const float* __restrict__ gi0, const float* __restrict__ W0P,
    const float* __restrict__ bh0, float* __restrict__ H0, int S0,
    const float* __restrict__ gi1, const float* __restrict__ W1P,
    const float* __restrict__ bh1, float* __restrict__ H1, int S1)
{
  const int blk = blockIdx.x;
  const float* gi; const float* WP; const float* bh; float* Hs; int S;
  if (blk < 32){ gi = gi0 + (size_t)blk*S0*450;      WP = W0P; bh = bh0;
                 Hs = H0 + (size_t)blk*S0*HID;       S = S0; }
  else         { int bb = blk-32;
                 gi = gi1 + (size_t)bb*S1*450;       WP = W1P; bh = bh1;
                 Hs = H1 + (size_t)bb*S1*HID;        S = S1; }
  __shared__ float h[152];
  __shared__ float gh[456];
  const int tid = threadIdx.x;
  R38(DECA)
  float br = 0.f;
  if (tid < 450){
    const float4* wp4 = (const float4*)(WP + (size_t)tid*152);
    R38(LDA)
    br = bh[tid];
  }
  if (tid < 152) h[tid] = 0.f;
  __syncthreads();
  const float4* h4 = (const float4*)h;
  for (int t=0;t<S;t++){
    float g0=0.f,g1=0.f,g2=0.f;
    if (tid < 150){
      const float* g = gi + (size_t)t*450;
      g0 = g[tid]; g1 = g[150+tid]; g2 = g[300+tid];
    }
    if (tid < 450){
      float a0=0.f,a1=0.f,a2=0.f,a3=0.f;
      R38(FMA_A)
      gh[tid] = br + (a0+a1) + (a2+a3);
    }
    __syncthreads();
    if (tid < 150){
      float r = sigm(g0 + gh[tid]);
      float z = sigm(g1 + gh[150+tid]);
      float n = tanh_f(g2 + r*gh[300+tid]);
      float hn = (1.f-z)*n + z*h[tid];
      h[tid] = hn;
      Hs[(size_t)t*HID + tid] = hn;
    }
    __syncthreads();
  }
}

__global__ void zero_hr0_kernel(float* __restrict__ Hr){
  int idx = blockIdx.x*blockDim.x + threadIdx.x;
  if (idx < NBATCH*300){
    int b = idx/300, k = idx - 300*b;
    Hr[(size_t)b*T1*300 + k] = 0.f;
  }
}

// ---- match scan: one block per (batch, dir).
__global__ __launch_bounds__(512)
__attribute__((amdgpu_waves_per_eu(2, 2)))
void match_scan_kernel(
    const float* __restrict__ pWp,   // [B,T,150]  Hp@Wp + gate_bias
    const float* __restrict__ whq,   // [B,J,150]  Hq@Wq
    const float* __restrict__ giXf,  // [B,T,450]  Hp@m_Wih_x^T + m_bih
    const float* __restrict__ giXr,
    const float* __restrict__ Pf,    // [B,J,450]  Hq@m_Wih_q^T
    const float* __restrict__ Pr,
    const float* __restrict__ mWhhP, const float* __restrict__ mrWhhP, // [450,152]
    const float* __restrict__ m_bhh, const float* __restrict__ mr_bhh,
    const float* __restrict__ WrTp,  // [150,156] transposed, seg-padded
    const float* __restrict__ wvec,  // [150]
    float* __restrict__ Hr)          // [B,401,300]
{
  const int b   = blockIdx.x;
  const int dir = blockIdx.y;
  const float* giX = dir ? giXr : giXf;
  const float* P   = dir ? Pr   : Pf;
  const float* WP  = dir ? mrWhhP : mWhhP;
  const float* bhh = dir ? mr_bhh : m_bhh;

  __shared__ float Pl[13500];      // 54 KB
  __shared__ float wl[152];
  __shared__ float h[152];
  __shared__ float pA[456];
  __shared__ float sc[32], attw[32];
  __shared__ float gis[456], ghs[456];

  const int tid = threadIdx.x;
  const int lane = tid & 63;
  const int wv = tid >> 6;

  R38(DECA)
  R13(DECR)
  float br = 0.f;
  const int kw  = (tid < 450) ? (tid % 150) : 0;
  const int seg = (tid < 450) ? (tid / 150) : 0;
  const int hb2 = seg*25;          // float2 index of h[seg*50]
  if (tid < 450){
    const float4* wp4 = (const float4*)(WP + (size_t)tid*152);
    R38(LDA)
    br = bhh[tid];
    const float4* wq4 = (const float4*)(WrTp + (size_t)kw*156 + seg*52);
    R13(LDR)
  }
  for (int e=tid; e<13500; e+=blockDim.x) Pl[e] = P[(size_t)b*13500 + e];
  if (tid < 152){ wl[tid] = (tid<150)?wvec[tid]:0.f; h[tid] = 0.f; }
  __syncthreads();
  const float4* h4 = (const float4*)h;
  const float2* h2 = (const float2*)h;

  const float* wq = whq + (size_t)b*JQ*150;
  for (int t=0;t<TLEN;t++){
    const int tt = dir ? (TLEN-1-t) : t;
    const float* pw = pWp + ((size_t)b*TLEN + tt)*150;
    float gv = (tid < 450) ? giX[((size_t)b*TLEN + tt)*450 + tid] : 0.f;
    float pw0 = pw[lane];
    float pw1 = pw[lane+64];
    float pw2 = (lane+128 < 150) ? pw[lane+128] : 0.f;

    // A: gh = bhh + h@Whh^T (regs) and Wr partials (regs)
    if (tid < 450){
      float a0=0.f,a1=0.f,a2=0.f,a3=0.f;
      R38(FMA_A)
      ghs[tid] = br + (a0+a1) + (a2+a3);
      float b0=0.f,b1=0.f,b2=0.f,b3=0.f;
      R13(FMA_R)
      pA[tid] = (b0+b1) + (b2+b3);
    }
    __syncthreads();

    // B: s[j] = sum_h w[h]*tanh(whq[j,h] + pWp[h] + hWr[h])
    for (int j=wv; j<JQ; j+=8){
      float acc = 0.f;
      {
        float hw = pA[lane] + pA[150+lane] + pA[300+lane];
        acc += wl[lane]*tanh_f(wq[j*150+lane] + pw0 + hw);
      }
      {
        int hh = lane+64;
        float hw = pA[hh] + pA[150+hh] + pA[300+hh];
        acc += wl[hh]*tanh_f(wq[j*150+hh] + pw1 + hw);
      }
      if (lane+128 < 150){
        int hh = lane+128;
        float hw = pA[hh] + pA[150+hh] + pA[300+hh];
        acc += wl[hh]*tanh_f(wq[j*150+hh] + pw2 + hw);
      }
      #pragma unroll
      for (int off=32; off; off>>=1) acc += __shfl_down(acc, off);
      if (lane==0) sc[j] = acc;
    }
    __syncthreads();

    // C: softmax over J=30
    if (tid < 64){
      float v = (tid < JQ) ? sc[tid] : -1e30f;
      float m = v;
      #pragma unroll
      for (int off=32; off; off>>=1) m = fmaxf(m, __shfl_down(m, off));
      m = __shfl(m, 0);
      float e = (tid < JQ) ? __expf(v-m) : 0.f;
      float s = e;
      #pragma unroll
      for (int off=32; off; off>>=1) s += __shfl_down(s, off);
      s = __shfl(s, 0);
      if (tid < JQ) attw[tid] = e/s;
    }
    __syncthreads();

    // D: gi = giX + sum_j attw[j]*P[j,:]
    if (tid < 450){
      float a0 = gv, a1 = 0.f;
      #pragma unroll
      for (int j=0;j<JQ;j+=2){
        a0 += attw[j]  *Pl[j*450+tid];
        a1 += attw[j+1]*Pl[(j+1)*450+tid];
      }
      gis[tid] = a0+a1;
    }
    __syncthreads();

    // E: GRU combine, write Hr[b, t+1, dir*150 + k]
    if (tid < 150){
      float r = sigm(gis[tid] + ghs[tid]);
      float z = sigm(gis[150+tid] + ghs[150+tid]);
      float n = tanh_f(gis[300+tid] + r*ghs[300+tid]);
      float hn = (1.f-z)*n + z*h[tid];
      h[tid] = hn;
      Hr[((size_t)b*T1 + (t+1))*300 + dir*150 + tid] = hn;
    }
    __syncthreads();
  }
}

// ---- pointer decoder
__global__ __launch_bounds__(512,2) void ptr_scan_kernel(
    const float* __restrict__ enc, const float* __restrict__ Hr,
    const float* __restrict__ W2, const float* __restrict__ pv,
    const float* __restrict__ dWih, const float* __restrict__ dWhh,
    const float* __restrict__ dbih, const float* __restrict__ dbhh,
    void* __restrict__ outv, const int* __restrict__ flag)
{
  const int b = blockIdx.x;
  const int tid = threadIdx.x;
  const int isbf = *flag;
  __shared__ float h[300], hW2[300], sl[T1], al[T1], c[300];
  __shared__ float gis[900], ghs[900];
  __shared__ float vl[300];
  __shared__ float red[8];
  if (tid < 300){ h[tid] = 0.f; vl[tid] = pv[tid]; }
  __syncthreads();
  for (int l=0;l<2;l++){
    if (tid < 300){
      float a0=0.f,a1=0.f;
      for (int i=0;i<300;i+=2){
        a0 += h[i]  *W2[(size_t)i*300+tid];
        a1 += h[i+1]*W2[(size_t)(i+1)*300+tid];
      }
      hW2[tid] = a0+a1;
    }
    __syncthreads();
    {
      const int wv = tid>>6, lane = tid&63;
      for (int t=wv; t<T1; t+=8){
        const float* er = enc + ((size_t)b*T1 + t)*300;
        float acc = 0.f;
        for (int k=lane; k<300; k+=64) acc += vl[k]*tanh_f(er[k] + hW2[k]);
        #pragma unroll
        for (int off=32; off; off>>=1) acc += __shfl_down(acc, off);
        if (lane==0) sl[t] = acc;
      }
    }
    __syncthreads();
    {
      float v = (tid < T1) ? sl[tid] : -1e30f;
      float m = v;
      #pragma unroll
      for (int off=32; off; off>>=1) m = fmaxf(m, __shfl_down(m, off));
      if ((tid&63)==0) red[tid>>6] = m;
      __syncthreads();
      float bm = fmaxf(fmaxf(fmaxf(red[0],red[1]),fmaxf(red[2],red[3])),
                       fmaxf(fmaxf(red[4],red[5]),fmaxf(red[6],red[7])));
      float e = (tid < T1) ? __expf(v-bm) : 0.f;
      float s = e;
      #pragma unroll
      for (int off=32; off; off>>=1) s += __shfl_down(s, off);
      __syncthreads();
      if ((tid&63)==0) red[tid>>6] = s;
      __syncthreads();
      float bs = red[0]+red[1]+red[2]+red[3]+red[4]+red[5]+red[6]+red[7];
      if (tid < T1){
        float a = e/bs;
        al[tid] = a;
        size_t oi = ((size_t)b*2 + l)*T1 + tid;
        if (isbf) ((__hip_bfloat16*)outv)[oi] = __float2bfloat16(a);
        else      ((float*)outv)[oi] = a;
      }
    }
    __syncthreads();
    if (tid < 300){
      float acc = 0.f;
      for (int t=0;t<T1;t++) acc += al[t]*Hr[((size_t)b*T1 + t)*300 + tid];
      c[tid] = acc;
    }
    __syncthreads();
    for (int k=tid; k<900; k+=blockDim.x){
      const float* wi = dWih + (size_t)k*300;
      const float* wh = dWhh + (size_t)k*300;
      float a0 = dbih[k], a1 = dbhh[k];
      for (int i=0;i<300;i++){ a0 += c[i]*wi[i]; a1 += h[i]*wh[i]; }
      gis[k] = a0; ghs[k] = a1;
    }
    __syncthreads();
    if (tid < 300){
      float r = sigm(gis[tid] + ghs[tid]);
      float z = sigm(gis[300+tid] + ghs[300+tid]);
      float n = tanh_f(gis[600+tid] + r*ghs[600+tid]);
      h[tid] = (1.f-z)*n + z*h[tid];
    }
    __syncthreads();
  }
}

} // namespace

extern "C" void kernel_launch(void* const* d_in, const int* in_sizes, int n_in,
                              void* d_out, int out_size, void* d_ws, size_t ws_size,
                              hipStream_t stream)
{
  (void)in_sizes; (void)n_in; (void)out_size; (void)ws_size;
  float* ws = (float*)d_ws;
  int* flag = (int*)d_ws;

  static const int wsz[NW] = {
    67500,67500,450,450,
    67500,67500,450,450,
    22500,22500,22500,150,150,1,
    135000,67500,450,450,
    135000,67500,450,450,
    90000,90000,300,
    270000,270000,900,900
  };
  WDesc desc;
  int cum = 0;
  for (int j=0;j<NW;j++){ desc.src[j] = d_in[3+j]; desc.off[j] = cum; cum += wsz[j]; }
  desc.off[NW] = cum;

  float* WB = ws + 16;
  const float* P_ctx_Wih = WB + desc.off[0];
  const float* P_ctx_Whh = WB + desc.off[1];
  const float* P_ctx_bih = WB + desc.off[2];
  const float* P_ctx_bhh = WB + desc.off[3];
  const float* P_q_Wih   = WB + desc.off[4];
  const float* P_q_Whh   = WB + desc.off[5];
  const float* P_q_bih   = WB + desc.off[6];
  const float* P_q_bhh   = WB + desc.off[7];
  const float* P_Wq      = WB + desc.off[8];
  const float* P_Wp      = WB + desc.off[9];
  const float* P_Wr      = WB + desc.off[10];
  const float* P_w       = WB + desc.off[11];
  const float* P_gb      = WB + desc.off[12];
  const float* P_m_Wih   = WB + desc.off[14];
  const float* P_m_Whh   = WB + desc.off[15];
  const float* P_m_bih   = WB + desc.off[16];
  const float* P_m_bhh   = WB + desc.off[17];
  const float* P_mr_Wih  = WB + desc.off[18];
  const float* P_mr_Whh  = WB + desc.off[19];
  const float* P_mr_bih  = WB + desc.off[20];
  const float* P_mr_bhh  = WB + desc.off[21];
  const float* P_W1      = WB + desc.off[22];
  const float* P_W2      = WB + desc.off[23];
  const float* P_pv      = WB + desc.off[24];
  const float* P_dWih    = WB + desc.off[25];
  const float* P_dWhh    = WB + desc.off[26];
  const float* P_dbih    = WB + desc.off[27];
  const float* P_dbhh    = WB + desc.off[28];

  // padded weight layouts
  size_t p = 16 + 1468512;
  float* ctxWhhP = ws + p; p += 68400;   // [450,152]
  float* qWhhP   = ws + p; p += 68400;
  float* mWhhP   = ws + p; p += 68400;
  float* mrWhhP  = ws + p; p += 68400;
  float* WrTp    = ws + p; p += 23400;   // [150,156]

  float* ctx_gi = ws + p; p += 5760000;
  float* q_gi   = ws + p; p += 432000;
  float* HpB    = ws + p; p += 1920000;
  float* HqB    = ws + p; p += 144000;
  float* whqB   = ws + p; p += 144000;
  float* PfB    = ws + p; p += 432000;
  float* PrB    = ws + p; p += 432000;
  float* pWpB   = ws + p; p += 1920000;
  float* giXfB  = ws + p; p += 5760000;
  float* giXrB  = ws + p; p += 5760000;
  float* HrB    = ws + p; p += 3849600;
  float* encB   = ctx_gi;                // reuse (dead by then)

  // 1) dtype sniff + weight conversion + padded layouts
  sniff_kernel<<<1,256,0,stream>>>((const unsigned int*)d_in[2], flag);
  convert_weights_kernel<<<512,256,0,stream>>>(desc, WB, flag);
  padrows_kernel<<<(450*152+255)/256,256,0,stream>>>(P_ctx_Whh, ctxWhhP, 450,150,152);
  padrows_kernel<<<(450*152+255)/256,256,0,stream>>>(P_q_Whh,   qWhhP,   450,150,152);
  padrows_kernel<<<(450*152+255)/256,256,0,stream>>>(P_m_Whh,   mWhhP,   450,150,152);
  padrows_kernel<<<(450*152+255)/256,256,0,stream>>>(P_mr_Whh,  mrWhhP,  450,150,152);
  wrt_kernel<<<(150*156+255)/256,256,0,stream>>>(P_Wr, WrTp);

  // 2) embedding + input projections for both encoders
  rowproj_kernel<<<1600,512,0,stream>>>(nullptr,(const int*)d_in[0], d_in[2], flag,
                                        P_ctx_Wih, P_ctx_bih, ctx_gi, 12800,450,150,1,150,0);
  rowproj_kernel<<<120,512,0,stream>>>(nullptr,(const int*)d_in[1], d_in[2], flag,
                                       P_q_Wih, P_q_bih, q_gi, 960,450,150,1,150,0);

  // 3) encoder scans (merged: 32 ctx blocks + 32 query blocks)
  gru_scan_kernel<<<64,512,0,stream>>>(ctx_gi, ctxWhhP, P_ctx_bhh, HpB, 400,
                                       q_gi,   qWhhP,   P_q_bhh,   HqB, 30);

  // 4) Hq/Hp-dependent precomputations
  rowproj_kernel<<<120,192,0,stream>>>(HqB,nullptr,nullptr,nullptr, P_Wq, nullptr,
                                       whqB, 960,150,150,0,150,0);
  rowproj_kernel<<<120,512,0,stream>>>(HqB,nullptr,nullptr,nullptr, P_m_Wih, nullptr,
                                       PfB, 960,450,150,1,300,150);
  rowproj_kernel<<<120,512,0,stream>>>(HqB,nullptr,nullptr,nullptr, P_mr_Wih, nullptr,
                                       PrB, 960,450,150,1,300,150);
  rowproj_kernel<<<1600,192,0,stream>>>(HpB,nullptr,nullptr,nullptr, P_Wp, P_gb,
                                        pWpB, 12800,150,150,0,150,0);
  rowproj_kernel<<<1600,512,0,stream>>>(HpB,nullptr,nullptr,nullptr, P_m_Wih, P_m_bih,
                                        giXfB, 12800,450,150,1,300,0);
  rowproj_kernel<<<1600,512,0,stream>>>(HpB,nullptr,nullptr,nullptr, P_mr_Wih, P_mr_bih,
                                        giXrB, 12800,450,150,1,300,0);

  // 5) match scans (fwd+bwd concurrent)
  zero_hr0_kernel<<<(NBATCH*300+511)/512,512,0,stream>>>(HrB);
  match_scan_kernel<<<dim3(NBATCH,2),512,0,stream>>>(pWpB, whqB, giXfB, giXrB,
                                                     PfB, PrB, mWhhP, mrWhhP,
                                                     P_m_bhh, P_mr_bhh, WrTp, P_w, HrB);

  // 6) pointer decoder
  rowproj_kernel<<<1604,320,0,stream>>>(HrB,nullptr,nullptr,nullptr, P_W1, nullptr,
                                        encB, 12832,300,300,0,300,0);
  ptr_scan_kernel<<<32,512,0,stream>>>(encB, HrB, P_W2, P_pv,
                                       P_dWih, P_dWhh, P_dbih, P_dbhh, d_out, flag);
}